// Round 3
// baseline (3003.484 us; speedup 1.0000x reference)
//
#include <hip/hip_runtime.h>
#include <cmath>

typedef __attribute__((ext_vector_type(8))) short bf16x8;
typedef __attribute__((ext_vector_type(4))) float f32x4;

constexpr int N_PTS = 16384;
constexpr int KK    = 30;       // kNN k
constexpr int NEDGE = 262144;
constexpr float NS  = 0.2f;     // leaky relu slope
constexpr int S_SL  = 8;        // candidate slices in pass1
constexpr int M_L   = 10;       // per-(slice,quad) approx list size
constexpr int CPQ   = S_SL * 4 * M_L;  // 320 superset candidates/query
constexpr int FD    = 8;        // LDS FIFO depth (16KB -> 8 blocks/CU)

__device__ inline short f2bf_rne(float f) {
  unsigned u = __float_as_uint(f);
  unsigned r = (u + 0x7fffu + ((u >> 16) & 1u)) >> 16;
  return (short)r;
}

// ---- sq (exact fp32, sequential order) + bf16 hi/lo split, zero-padded -----
template<int C, int CP>
__global__ __launch_bounds__(256) void sqsplit(const float* __restrict__ X,
    float* __restrict__ sqv, short* __restrict__ Xh, short* __restrict__ Xl) {
  int p = blockIdx.x * 256 + threadIdx.x;
  float s = 0.f;
#pragma unroll
  for (int c = 0; c < C; ++c) {
    float v = X[(size_t)p * C + c];
    s = fmaf(v, v, s);
    short h = f2bf_rne(v);
    float hf = __uint_as_float(((unsigned)(unsigned short)h) << 16);
    short l = f2bf_rne(v - hf);
    Xh[(size_t)p * CP + c] = h;
    Xl[(size_t)p * CP + c] = l;
  }
#pragma unroll
  for (int c = C; c < CP; ++c) {
    Xh[(size_t)p * CP + c] = 0;
    Xl[(size_t)p * CP + c] = 0;
  }
  sqv[p] = s;
}

// ---- pass 1: MFMA approx distances, per-(slice,quad) top-M index superset --
// wave = 16 queries; per 16-cand tile: 3*KT mfma (hi*hi + hi*lo + lo*hi).
// key = sqc - 2*dot (sqq const per query -> rank-equivalent).
// grid (256, 8) = 2048 blocks = 8 blocks/CU -> 32 waves/CU.
template<int KT>
__global__ __launch_bounds__(256, 8) void knn_pass1(
    const short* __restrict__ Xh, const short* __restrict__ Xl,
    const float* __restrict__ sqv, int* __restrict__ cand) {
  constexpr int CP = KT * 32;
  __shared__ float fifo_k[FD][256];
  __shared__ int   fifo_j[FD][256];
  const int tid  = threadIdx.x;
  const int lane = tid & 63;
  const int wv   = tid >> 6;
  const int col  = lane & 15;     // query within tile
  const int quad = lane >> 4;     // 0..3 (k-group / C-row group)
  const int q    = blockIdx.x * 64 + wv * 16 + col;
  const int slice = blockIdx.y;
  const int slen = N_PTS / S_SL;
  const int c0 = slice * slen;

  bf16x8 bh[KT], bl[KT];
#pragma unroll
  for (int kt = 0; kt < KT; ++kt) {
    bh[kt] = *(const bf16x8*)(Xh + (size_t)q * CP + kt * 32 + quad * 8);
    bl[kt] = *(const bf16x8*)(Xl + (size_t)q * CP + kt * 32 + quad * 8);
  }

  float kd[M_L]; int ki[M_L];
#pragma unroll
  for (int t = 0; t < M_L; ++t) { kd[t] = __builtin_inff(); ki[t] = -1; }
  int cnt = 0;

  auto flush = [&]() {
    const int m = cnt;
    for (int e = 0; e < m; ++e) {
      float ck = fifo_k[e][tid];
      int   cj = fifo_j[e][tid];
      if (ck < kd[M_L - 1]) {
#pragma unroll
        for (int t = 0; t < M_L; ++t) {
          float ok = kd[t]; int oi = ki[t];
          bool cl = ck < ok;
          kd[t] = cl ? ck : ok; ki[t] = cl ? cj : oi;
          ck = cl ? ok : ck;   cj = cl ? oi : cj;
        }
      }
    }
    cnt = 0;
  };

  for (int ct = 0; ct < slen; ct += 16) {
    const int cb = c0 + ct;
    const size_t arow = (size_t)(cb + col) * CP + quad * 8;
    bf16x8 ah[KT], al[KT];
#pragma unroll
    for (int kt = 0; kt < KT; ++kt) {
      ah[kt] = *(const bf16x8*)(Xh + arow + kt * 32);
      al[kt] = *(const bf16x8*)(Xl + arow + kt * 32);
    }
    f32x4 sc = *(const f32x4*)(sqv + cb + quad * 4);
    f32x4 hh = {0.f, 0.f, 0.f, 0.f}, hl = {0.f, 0.f, 0.f, 0.f}, lh = {0.f, 0.f, 0.f, 0.f};
#pragma unroll
    for (int kt = 0; kt < KT; ++kt) {
      hh = __builtin_amdgcn_mfma_f32_16x16x32_bf16(ah[kt], bh[kt], hh, 0, 0, 0);
      hl = __builtin_amdgcn_mfma_f32_16x16x32_bf16(ah[kt], bl[kt], hl, 0, 0, 0);
      lh = __builtin_amdgcn_mfma_f32_16x16x32_bf16(al[kt], bh[kt], lh, 0, 0, 0);
    }
#pragma unroll
    for (int r = 0; r < 4; ++r) {
      float dot = hh[r] + (hl[r] + lh[r]);
      float key = fmaf(dot, -2.f, sc[r]);
      if (key < kd[M_L - 1]) {     // stale bound ok; rechecked at flush
        fifo_k[cnt][tid] = key;
        fifo_j[cnt][tid] = cb + quad * 4 + r;
        ++cnt;
      }
    }
    // <=4 pushes between checks, trigger at FD-3=5 -> cnt <= 8 = FD, safe
    if (__ballot(cnt >= FD - 3) != 0ULL) flush();
  }
  flush();

  int* o = cand + ((size_t)q * S_SL + slice) * (4 * M_L) + quad * M_L;
#pragma unroll
  for (int t = 0; t < M_L; ++t) o[t] = ki[t];
}

// ---- pass 2: exact fp32 re-rank of the 320-candidate superset --------------
template<int C>
__global__ __launch_bounds__(256) void knn_pass2(
    const float* __restrict__ X, const float* __restrict__ sqv,
    const int* __restrict__ cand, int* __restrict__ knn) {
  const int lane = threadIdx.x & 63, wv = threadIdx.x >> 6;
  const int q = blockIdx.x * 4 + wv;
  constexpr int PL = CPQ / 64;   // 5
  const float sqq = sqv[q];
  const float* __restrict__ xq = X + (size_t)q * C;   // wave-uniform -> scalar
  float d[PL]; int id[PL];
#pragma unroll
  for (int u = 0; u < PL; ++u) {
    const int j = cand[(size_t)q * CPQ + lane * PL + u];
    id[u] = j;
    const float* __restrict__ xj = X + (size_t)j * C;
    float dot;
    if constexpr (C % 4 == 0) {
      float a0 = 0.f, a1 = 0.f, a2 = 0.f, a3 = 0.f;
#pragma unroll
      for (int c = 0; c < C; c += 4) {
        a0 = fmaf(xq[c + 0], xj[c + 0], a0);
        a1 = fmaf(xq[c + 1], xj[c + 1], a1);
        a2 = fmaf(xq[c + 2], xj[c + 2], a2);
        a3 = fmaf(xq[c + 3], xj[c + 3], a3);
      }
      dot = (a0 + a1) + (a2 + a3);
    } else {
      dot = 0.f;
#pragma unroll
      for (int c = 0; c < C; ++c) dot = fmaf(xq[c], xj[c], dot);
    }
    d[u] = (sqq + sqv[j]) - 2.f * dot;
  }
  for (int r = 0; r < KK; ++r) {
    float bd = d[0]; int bi = id[0];
#pragma unroll
    for (int u = 1; u < PL; ++u) {
      bool c = (d[u] < bd) || (d[u] == bd && id[u] < bi);
      bd = c ? d[u] : bd; bi = c ? id[u] : bi;
    }
#pragma unroll
    for (int off = 32; off; off >>= 1) {
      float od = __shfl_xor(bd, off, 64);
      int   oi = __shfl_xor(bi, off, 64);
      bool c = (od < bd) || (od == bd && oi < bi);
      bd = c ? od : bd; bi = c ? oi : bi;
    }
    if (lane == 0) knn[(size_t)q * KK + r] = bi;
#pragma unroll
    for (int u = 0; u < PL; ++u) if (id[u] == bi) d[u] = __builtin_inff();
  }
}

// ---- DynamicEdgeConv: max_k leaky([xi, xj-xi] @ W + b) ---------------------
template<int C, int PPW>
__global__ __launch_bounds__(256) void edge_conv(
    const float* __restrict__ X, const int* __restrict__ knn,
    const float* __restrict__ W, const float* __restrict__ B,
    float* __restrict__ Y) {
  const int wv = __builtin_amdgcn_readfirstlane(threadIdx.x >> 6);
  const int lane = threadIdx.x & 63;
  float wd[C], wj[C];
#pragma unroll
  for (int c = 0; c < C; ++c) {
    float w0 = W[c * 64 + lane];
    float w1 = W[(C + c) * 64 + lane];
    wd[c] = w0 - w1; wj[c] = w1;
  }
  const float bb = B[lane];
  const int p0 = (blockIdx.x * 4 + wv) * PPW;
  for (int pp = 0; pp < PPW; ++pp) {
    const int p = p0 + pp;
    const float* __restrict__ xi = X + (size_t)p * C;
    float base = bb;
#pragma unroll
    for (int c = 0; c < C; ++c) base = fmaf(xi[c], wd[c], base);
    float m = -__builtin_inff();
    for (int n = 0; n < KK; ++n) {
      const int j = __builtin_amdgcn_readfirstlane(knn[(size_t)p * KK + n]);
      const float* __restrict__ xj = X + (size_t)j * C;
      float acc;
      if constexpr (C % 4 == 0) {
        float a0 = 0.f, a1 = 0.f, a2 = 0.f, a3 = 0.f;
#pragma unroll
        for (int c = 0; c < C; c += 4) {
          a0 = fmaf(xj[c + 0], wj[c + 0], a0);
          a1 = fmaf(xj[c + 1], wj[c + 1], a1);
          a2 = fmaf(xj[c + 2], wj[c + 2], a2);
          a3 = fmaf(xj[c + 3], wj[c + 3], a3);
        }
        acc = base + ((a0 + a1) + (a2 + a3));
      } else {
        acc = base;
#pragma unroll
        for (int c = 0; c < C; ++c) acc = fmaf(xj[c], wj[c], acc);
      }
      acc = acc > 0.f ? acc : NS * acc;
      m = fmaxf(m, acc);
    }
    Y[(size_t)p * 64 + lane] = m;
  }
}

// ---- edge head --------------------------------------------------------------
template<int EPW>
__global__ __launch_bounds__(256) void edge_head(
    const float* __restrict__ X, const int* __restrict__ ei,
    const float* __restrict__ Wh1, const float* __restrict__ bh1,
    const float* __restrict__ Wh2, const float* __restrict__ bh2,
    float* __restrict__ out) {
  const int wv = __builtin_amdgcn_readfirstlane(threadIdx.x >> 6);
  const int lane = threadIdx.x & 63;
  float w0[64], w1[64];
#pragma unroll
  for (int c = 0; c < 64; ++c) {
    w0[c] = Wh1[c * 64 + lane];
    w1[c] = Wh1[(64 + c) * 64 + lane];
  }
  const float bb = bh1[lane];
  const float wv2 = Wh2[lane];
  const float b2 = bh2[0];
  const int e0 = (blockIdx.x * 4 + wv) * EPW;
  for (int ee = 0; ee < EPW; ++ee) {
    const int e = e0 + ee;
    const int a = ei[e], b = ei[NEDGE + e];
    const int v0 = __builtin_amdgcn_readfirstlane(min(a, b));
    const int v1 = __builtin_amdgcn_readfirstlane(max(a, b));
    const float* __restrict__ f0 = X + (size_t)v0 * 64;
    const float* __restrict__ f1 = X + (size_t)v1 * 64;
    float a0 = 0.f, a1 = 0.f, a2 = 0.f, a3 = 0.f;
#pragma unroll
    for (int c = 0; c < 64; c += 4) {
      a0 = fmaf(f0[c + 0], w0[c + 0], a0);
      a1 = fmaf(f0[c + 1], w0[c + 1], a1);
      a2 = fmaf(f0[c + 2], w0[c + 2], a2);
      a3 = fmaf(f0[c + 3], w0[c + 3], a3);
    }
#pragma unroll
    for (int c = 0; c < 64; c += 4) {
      a0 = fmaf(f1[c + 0], w1[c + 0], a0);
      a1 = fmaf(f1[c + 1], w1[c + 1], a1);
      a2 = fmaf(f1[c + 2], w1[c + 2], a2);
      a3 = fmaf(f1[c + 3], w1[c + 3], a3);
    }
    float h = bb + ((a0 + a1) + (a2 + a3));
    h = h > 0.f ? h : NS * h;
    float z = h * wv2;
#pragma unroll
    for (int off = 32; off; off >>= 1) z += __shfl_xor(z, off, 64);
    if (lane == 0) out[e] = 1.f / (1.f + expf(-(z + b2)));
  }
}

// -----------------------------------------------------------------------------
extern "C" void kernel_launch(void* const* d_in, const int* in_sizes, int n_in,
                              void* d_out, int out_size, void* d_ws, size_t ws_size,
                              hipStream_t stream) {
  const float* x   = (const float*)d_in[0];
  const int*   ei  = (const int*)d_in[1];
  const float* W1  = (const float*)d_in[2];
  const float* b1  = (const float*)d_in[3];
  const float* W2  = (const float*)d_in[4];
  const float* b2  = (const float*)d_in[5];
  const float* W3  = (const float*)d_in[6];
  const float* b3  = (const float*)d_in[7];
  const float* Wh1 = (const float*)d_in[8];
  const float* bh1 = (const float*)d_in[9];
  const float* Wh2 = (const float*)d_in[10];
  const float* bh2 = (const float*)d_in[11];
  float* out = (float*)d_out;

  char* ws = (char*)d_ws;
  float* xA  = (float*)ws; ws += (size_t)N_PTS * 64 * 4;      // 4 MB
  float* xB  = (float*)ws; ws += (size_t)N_PTS * 64 * 4;      // 4 MB
  float* sqb = (float*)ws; ws += (size_t)N_PTS * 4;
  int*   knn = (int*)ws;   ws += (size_t)N_PTS * KK * 4;      // 1.9 MB
  short* Xh  = (short*)ws; ws += (size_t)N_PTS * 64 * 2;      // 2 MB
  short* Xl  = (short*)ws; ws += (size_t)N_PTS * 64 * 2;      // 2 MB
  int*  cand = (int*)ws;   ws += (size_t)N_PTS * CPQ * 4;     // 21 MB
  (void)ws_size; (void)in_sizes; (void)n_in; (void)out_size;

  // ---- conv1 (C=3, padded to K=32) ----
  sqsplit<3, 32><<<N_PTS / 256, 256, 0, stream>>>(x, sqb, Xh, Xl);
  knn_pass1<1><<<dim3(N_PTS / 64, S_SL), 256, 0, stream>>>(Xh, Xl, sqb, cand);
  knn_pass2<3><<<N_PTS / 4, 256, 0, stream>>>(x, sqb, cand, knn);
  edge_conv<3, 4><<<N_PTS / 16, 256, 0, stream>>>(x, knn, W1, b1, xA);
  // ---- conv2 (C=64) ----
  sqsplit<64, 64><<<N_PTS / 256, 256, 0, stream>>>(xA, sqb, Xh, Xl);
  knn_pass1<2><<<dim3(N_PTS / 64, S_SL), 256, 0, stream>>>(Xh, Xl, sqb, cand);
  knn_pass2<64><<<N_PTS / 4, 256, 0, stream>>>(xA, sqb, cand, knn);
  edge_conv<64, 4><<<N_PTS / 16, 256, 0, stream>>>(xA, knn, W2, b2, xB);
  // ---- conv3 (C=64) ----
  sqsplit<64, 64><<<N_PTS / 256, 256, 0, stream>>>(xB, sqb, Xh, Xl);
  knn_pass1<2><<<dim3(N_PTS / 64, S_SL), 256, 0, stream>>>(Xh, Xl, sqb, cand);
  knn_pass2<64><<<N_PTS / 4, 256, 0, stream>>>(xB, sqb, cand, knn);
  edge_conv<64, 4><<<N_PTS / 16, 256, 0, stream>>>(xB, knn, W3, b3, xA);
  // ---- edge head ----
  edge_head<16><<<NEDGE / 64, 256, 0, stream>>>(xA, ei, Wh1, bh1, Wh2, bh2, out);
}

// Round 4
// 2110.212 us; speedup vs baseline: 1.4233x; 1.4233x over previous
//
#include <hip/hip_runtime.h>
#include <cmath>

typedef __attribute__((ext_vector_type(8))) short bf16x8;
typedef __attribute__((ext_vector_type(4))) float f32x4;

constexpr int N_PTS = 16384;
constexpr int KK    = 30;       // kNN k
constexpr int NEDGE = 262144;
constexpr float NS  = 0.2f;     // leaky relu slope
constexpr int S_SL  = 4;        // candidate slices in pass1
constexpr int M_L   = 12;       // per-(slice,quad) approx list size
constexpr int CPQ   = S_SL * 4 * M_L;  // 192 superset candidates/query
constexpr int FD    = 16;       // LDS FIFO depth

__device__ inline short f2bf_rne(float f) {
  unsigned u = __float_as_uint(f);
  unsigned r = (u + 0x7fffu + ((u >> 16) & 1u)) >> 16;
  return (short)r;
}

// ---- sq (exact fp32, sequential order) + bf16 hi/lo split, zero-padded -----
template<int C, int CP>
__global__ __launch_bounds__(256) void sqsplit(const float* __restrict__ X,
    float* __restrict__ sqv, short* __restrict__ Xh, short* __restrict__ Xl) {
  int p = blockIdx.x * 256 + threadIdx.x;
  float s = 0.f;
#pragma unroll
  for (int c = 0; c < C; ++c) {
    float v = X[(size_t)p * C + c];
    s = fmaf(v, v, s);
    short h = f2bf_rne(v);
    float hf = __uint_as_float(((unsigned)(unsigned short)h) << 16);
    short l = f2bf_rne(v - hf);
    Xh[(size_t)p * CP + c] = h;
    Xl[(size_t)p * CP + c] = l;
  }
#pragma unroll
  for (int c = C; c < CP; ++c) {
    Xh[(size_t)p * CP + c] = 0;
    Xl[(size_t)p * CP + c] = 0;
  }
  sqv[p] = s;
}

// ---- pass 1: MFMA approx distances, per-(slice,quad) top-M index superset --
// wave = 16 queries; per 16-cand tile: 3*KT mfma (hi*hi + hi*lo + lo*hi).
// key = sqc - 2*dot (sqq const per query -> rank-equivalent).
// Distance-2 software pipeline: 4 register tile-buffers, loads issued two
// compute phases ahead (covers ~200cy L2 latency); modulo-4 unroll, no moves.
template<int KT>
__global__ __launch_bounds__(256) void knn_pass1(
    const short* __restrict__ Xh, const short* __restrict__ Xl,
    const float* __restrict__ sqv, int* __restrict__ cand) {
  constexpr int CP = KT * 32;
  __shared__ float fifo_k[FD][256];
  __shared__ int   fifo_j[FD][256];
  const int tid  = threadIdx.x;
  const int lane = tid & 63;
  const int wv   = tid >> 6;
  const int col  = lane & 15;     // query within tile
  const int quad = lane >> 4;     // 0..3 (k-group / C-row group)
  const int q    = blockIdx.x * 64 + wv * 16 + col;
  const int slice = blockIdx.y;
  const int slen = N_PTS / S_SL;
  const int c0 = slice * slen;

  bf16x8 bh[KT], bl[KT];
#pragma unroll
  for (int kt = 0; kt < KT; ++kt) {
    bh[kt] = *(const bf16x8*)(Xh + (size_t)q * CP + kt * 32 + quad * 8);
    bl[kt] = *(const bf16x8*)(Xl + (size_t)q * CP + kt * 32 + quad * 8);
  }

  float kd[M_L]; int ki[M_L];
#pragma unroll
  for (int t = 0; t < M_L; ++t) { kd[t] = __builtin_inff(); ki[t] = -1; }
  int cnt = 0;

  auto flush = [&]() {
    const int m = cnt;
    for (int e = 0; e < m; ++e) {
      float ck = fifo_k[e][tid];
      int   cj = fifo_j[e][tid];
      if (ck < kd[M_L - 1]) {
#pragma unroll
        for (int t = 0; t < M_L; ++t) {
          float ok = kd[t]; int oi = ki[t];
          bool cl = ck < ok;
          kd[t] = cl ? ck : ok; ki[t] = cl ? cj : oi;
          ck = cl ? ok : ck;   cj = cl ? oi : cj;
        }
      }
    }
    cnt = 0;
  };

  // per-lane A-side base pointers (row = c0+col within tile, then +16 rows/tile)
  const short* pH = Xh + ((size_t)(c0 + col)) * CP + quad * 8;
  const short* pL = Xl + ((size_t)(c0 + col)) * CP + quad * 8;
  const float* pS = sqv + c0 + quad * 4;
  constexpr int STEP = 16 * CP;   // shorts per tile step

  bf16x8 h0[KT], l0[KT], h1[KT], l1[KT], h2[KT], l2[KT], h3[KT], l3[KT];
  f32x4 s0, s1, s2, s3;

  auto loadT = [&](bf16x8 (&h)[KT], bf16x8 (&l)[KT], f32x4& s, int tt) {
    const short* ph = pH + (size_t)tt * STEP;
    const short* pl = pL + (size_t)tt * STEP;
#pragma unroll
    for (int kt = 0; kt < KT; ++kt) {
      h[kt] = *(const bf16x8*)(ph + kt * 32);
      l[kt] = *(const bf16x8*)(pl + kt * 32);
    }
    s = *(const f32x4*)(pS + tt * 16);
  };

  auto compute = [&](bf16x8 (&h)[KT], bf16x8 (&l)[KT], f32x4& s, int tt) {
    f32x4 hh = {0.f, 0.f, 0.f, 0.f}, hl = {0.f, 0.f, 0.f, 0.f}, lh = {0.f, 0.f, 0.f, 0.f};
#pragma unroll
    for (int kt = 0; kt < KT; ++kt) {
      hh = __builtin_amdgcn_mfma_f32_16x16x32_bf16(h[kt], bh[kt], hh, 0, 0, 0);
      hl = __builtin_amdgcn_mfma_f32_16x16x32_bf16(h[kt], bl[kt], hl, 0, 0, 0);
      lh = __builtin_amdgcn_mfma_f32_16x16x32_bf16(l[kt], bh[kt], lh, 0, 0, 0);
    }
    const int cb = c0 + tt * 16;
#pragma unroll
    for (int r = 0; r < 4; ++r) {
      float dot = hh[r] + (hl[r] + lh[r]);
      float key = fmaf(dot, -2.f, s[r]);
      if (key < kd[M_L - 1]) {     // stale bound ok; rechecked at flush
        fifo_k[cnt][tid] = key;
        fifo_j[cnt][tid] = cb + quad * 4 + r;
        ++cnt;
      }
    }
    // <=4 pushes between checks, trigger at FD-3 -> never overflows
    if (__ballot(cnt >= FD - 3) != 0ULL) flush();
  };

  const int NT = slen / 16;       // 256: divisible by 4
  loadT(h0, l0, s0, 0);
  loadT(h1, l1, s1, 1);
  for (int t = 0; t < NT; t += 4) {
    loadT(h2, l2, s2, t + 2);
    compute(h0, l0, s0, t);
    loadT(h3, l3, s3, t + 3);
    compute(h1, l1, s1, t + 1);
    loadT(h0, l0, s0, (t + 4 < NT) ? t + 4 : 0);
    compute(h2, l2, s2, t + 2);
    loadT(h1, l1, s1, (t + 5 < NT) ? t + 5 : 0);
    compute(h3, l3, s3, t + 3);
  }
  flush();

  int* o = cand + ((size_t)q * S_SL + slice) * (4 * M_L) + quad * M_L;
#pragma unroll
  for (int t = 0; t < M_L; ++t) o[t] = ki[t];
}

// ---- pass 2: exact fp32 re-rank of the 192-candidate superset --------------
template<int C>
__global__ __launch_bounds__(256) void knn_pass2(
    const float* __restrict__ X, const float* __restrict__ sqv,
    const int* __restrict__ cand, int* __restrict__ knn) {
  const int lane = threadIdx.x & 63, wv = threadIdx.x >> 6;
  const int q = blockIdx.x * 4 + wv;
  constexpr int PL = CPQ / 64;   // 3
  const float sqq = sqv[q];
  const float* __restrict__ xq = X + (size_t)q * C;   // wave-uniform -> scalar
  float d[PL]; int id[PL];
#pragma unroll
  for (int u = 0; u < PL; ++u) {
    const int j = cand[(size_t)q * CPQ + lane * PL + u];
    id[u] = j;
    const float* __restrict__ xj = X + (size_t)j * C;
    float dot;
    if constexpr (C % 4 == 0) {
      float a0 = 0.f, a1 = 0.f, a2 = 0.f, a3 = 0.f;
#pragma unroll
      for (int c = 0; c < C; c += 4) {
        a0 = fmaf(xq[c + 0], xj[c + 0], a0);
        a1 = fmaf(xq[c + 1], xj[c + 1], a1);
        a2 = fmaf(xq[c + 2], xj[c + 2], a2);
        a3 = fmaf(xq[c + 3], xj[c + 3], a3);
      }
      dot = (a0 + a1) + (a2 + a3);
    } else {
      dot = 0.f;
#pragma unroll
      for (int c = 0; c < C; ++c) dot = fmaf(xq[c], xj[c], dot);
    }
    d[u] = (sqq + sqv[j]) - 2.f * dot;
  }
  for (int r = 0; r < KK; ++r) {
    float bd = d[0]; int bi = id[0];
#pragma unroll
    for (int u = 1; u < PL; ++u) {
      bool c = (d[u] < bd) || (d[u] == bd && id[u] < bi);
      bd = c ? d[u] : bd; bi = c ? id[u] : bi;
    }
#pragma unroll
    for (int off = 32; off; off >>= 1) {
      float od = __shfl_xor(bd, off, 64);
      int   oi = __shfl_xor(bi, off, 64);
      bool c = (od < bd) || (od == bd && oi < bi);
      bd = c ? od : bd; bi = c ? oi : bi;
    }
    if (lane == 0) knn[(size_t)q * KK + r] = bi;
#pragma unroll
    for (int u = 0; u < PL; ++u) if (id[u] == bi) d[u] = __builtin_inff();
  }
}

// ---- DynamicEdgeConv: max_k leaky([xi, xj-xi] @ W + b) ---------------------
template<int C, int PPW>
__global__ __launch_bounds__(256) void edge_conv(
    const float* __restrict__ X, const int* __restrict__ knn,
    const float* __restrict__ W, const float* __restrict__ B,
    float* __restrict__ Y) {
  const int wv = __builtin_amdgcn_readfirstlane(threadIdx.x >> 6);
  const int lane = threadIdx.x & 63;
  float wd[C], wj[C];
#pragma unroll
  for (int c = 0; c < C; ++c) {
    float w0 = W[c * 64 + lane];
    float w1 = W[(C + c) * 64 + lane];
    wd[c] = w0 - w1; wj[c] = w1;
  }
  const float bb = B[lane];
  const int p0 = (blockIdx.x * 4 + wv) * PPW;
  for (int pp = 0; pp < PPW; ++pp) {
    const int p = p0 + pp;
    const float* __restrict__ xi = X + (size_t)p * C;
    float base = bb;
#pragma unroll
    for (int c = 0; c < C; ++c) base = fmaf(xi[c], wd[c], base);
    float m = -__builtin_inff();
    for (int n = 0; n < KK; ++n) {
      const int j = __builtin_amdgcn_readfirstlane(knn[(size_t)p * KK + n]);
      const float* __restrict__ xj = X + (size_t)j * C;
      float acc;
      if constexpr (C % 4 == 0) {
        float a0 = 0.f, a1 = 0.f, a2 = 0.f, a3 = 0.f;
#pragma unroll
        for (int c = 0; c < C; c += 4) {
          a0 = fmaf(xj[c + 0], wj[c + 0], a0);
          a1 = fmaf(xj[c + 1], wj[c + 1], a1);
          a2 = fmaf(xj[c + 2], wj[c + 2], a2);
          a3 = fmaf(xj[c + 3], wj[c + 3], a3);
        }
        acc = base + ((a0 + a1) + (a2 + a3));
      } else {
        acc = base;
#pragma unroll
        for (int c = 0; c < C; ++c) acc = fmaf(xj[c], wj[c], acc);
      }
      acc = acc > 0.f ? acc : NS * acc;
      m = fmaxf(m, acc);
    }
    Y[(size_t)p * 64 + lane] = m;
  }
}

// ---- edge head --------------------------------------------------------------
template<int EPW>
__global__ __launch_bounds__(256) void edge_head(
    const float* __restrict__ X, const int* __restrict__ ei,
    const float* __restrict__ Wh1, const float* __restrict__ bh1,
    const float* __restrict__ Wh2, const float* __restrict__ bh2,
    float* __restrict__ out) {
  const int wv = __builtin_amdgcn_readfirstlane(threadIdx.x >> 6);
  const int lane = threadIdx.x & 63;
  float w0[64], w1[64];
#pragma unroll
  for (int c = 0; c < 64; ++c) {
    w0[c] = Wh1[c * 64 + lane];
    w1[c] = Wh1[(64 + c) * 64 + lane];
  }
  const float bb = bh1[lane];
  const float wv2 = Wh2[lane];
  const float b2 = bh2[0];
  const int e0 = (blockIdx.x * 4 + wv) * EPW;
  for (int ee = 0; ee < EPW; ++ee) {
    const int e = e0 + ee;
    const int a = ei[e], b = ei[NEDGE + e];
    const int v0 = __builtin_amdgcn_readfirstlane(min(a, b));
    const int v1 = __builtin_amdgcn_readfirstlane(max(a, b));
    const float* __restrict__ f0 = X + (size_t)v0 * 64;
    const float* __restrict__ f1 = X + (size_t)v1 * 64;
    float a0 = 0.f, a1 = 0.f, a2 = 0.f, a3 = 0.f;
#pragma unroll
    for (int c = 0; c < 64; c += 4) {
      a0 = fmaf(f0[c + 0], w0[c + 0], a0);
      a1 = fmaf(f0[c + 1], w0[c + 1], a1);
      a2 = fmaf(f0[c + 2], w0[c + 2], a2);
      a3 = fmaf(f0[c + 3], w0[c + 3], a3);
    }
#pragma unroll
    for (int c = 0; c < 64; c += 4) {
      a0 = fmaf(f1[c + 0], w1[c + 0], a0);
      a1 = fmaf(f1[c + 1], w1[c + 1], a1);
      a2 = fmaf(f1[c + 2], w1[c + 2], a2);
      a3 = fmaf(f1[c + 3], w1[c + 3], a3);
    }
    float h = bb + ((a0 + a1) + (a2 + a3));
    h = h > 0.f ? h : NS * h;
    float z = h * wv2;
#pragma unroll
    for (int off = 32; off; off >>= 1) z += __shfl_xor(z, off, 64);
    if (lane == 0) out[e] = 1.f / (1.f + expf(-(z + b2)));
  }
}

// -----------------------------------------------------------------------------
extern "C" void kernel_launch(void* const* d_in, const int* in_sizes, int n_in,
                              void* d_out, int out_size, void* d_ws, size_t ws_size,
                              hipStream_t stream) {
  const float* x   = (const float*)d_in[0];
  const int*   ei  = (const int*)d_in[1];
  const float* W1  = (const float*)d_in[2];
  const float* b1  = (const float*)d_in[3];
  const float* W2  = (const float*)d_in[4];
  const float* b2  = (const float*)d_in[5];
  const float* W3  = (const float*)d_in[6];
  const float* b3  = (const float*)d_in[7];
  const float* Wh1 = (const float*)d_in[8];
  const float* bh1 = (const float*)d_in[9];
  const float* Wh2 = (const float*)d_in[10];
  const float* bh2 = (const float*)d_in[11];
  float* out = (float*)d_out;

  char* ws = (char*)d_ws;
  float* xA  = (float*)ws; ws += (size_t)N_PTS * 64 * 4;      // 4 MB
  float* xB  = (float*)ws; ws += (size_t)N_PTS * 64 * 4;      // 4 MB
  float* sqb = (float*)ws; ws += (size_t)N_PTS * 4;
  int*   knn = (int*)ws;   ws += (size_t)N_PTS * KK * 4;      // 1.9 MB
  short* Xh  = (short*)ws; ws += (size_t)N_PTS * 64 * 2;      // 2 MB
  short* Xl  = (short*)ws; ws += (size_t)N_PTS * 64 * 2;      // 2 MB
  int*  cand = (int*)ws;   ws += (size_t)N_PTS * CPQ * 4;     // 12.6 MB
  (void)ws_size; (void)in_sizes; (void)n_in; (void)out_size;

  // ---- conv1 (C=3, padded to K=32) ----
  sqsplit<3, 32><<<N_PTS / 256, 256, 0, stream>>>(x, sqb, Xh, Xl);
  knn_pass1<1><<<dim3(N_PTS / 64, S_SL), 256, 0, stream>>>(Xh, Xl, sqb, cand);
  knn_pass2<3><<<N_PTS / 4, 256, 0, stream>>>(x, sqb, cand, knn);
  edge_conv<3, 4><<<N_PTS / 16, 256, 0, stream>>>(x, knn, W1, b1, xA);
  // ---- conv2 (C=64) ----
  sqsplit<64, 64><<<N_PTS / 256, 256, 0, stream>>>(xA, sqb, Xh, Xl);
  knn_pass1<2><<<dim3(N_PTS / 64, S_SL), 256, 0, stream>>>(Xh, Xl, sqb, cand);
  knn_pass2<64><<<N_PTS / 4, 256, 0, stream>>>(xA, sqb, cand, knn);
  edge_conv<64, 4><<<N_PTS / 16, 256, 0, stream>>>(xA, knn, W2, b2, xB);
  // ---- conv3 (C=64) ----
  sqsplit<64, 64><<<N_PTS / 256, 256, 0, stream>>>(xB, sqb, Xh, Xl);
  knn_pass1<2><<<dim3(N_PTS / 64, S_SL), 256, 0, stream>>>(Xh, Xl, sqb, cand);
  knn_pass2<64><<<N_PTS / 4, 256, 0, stream>>>(xB, sqb, cand, knn);
  edge_conv<64, 4><<<N_PTS / 16, 256, 0, stream>>>(xB, knn, W3, b3, xA);
  // ---- edge head ----
  edge_head<16><<<NEDGE / 64, 256, 0, stream>>>(xA, ei, Wh1, bh1, Wh2, bh2, out);
}